// Round 7
// baseline (38.705 us; speedup 1.0000x reference)
//
#include <hip/hip_runtime.h>

// UpsampleFlow2: Gaussian Nadaraya-Watson upsampling.
// out [B,3,N] = (sum_s k*f)/(sum_s k), k = exp(-|x-y|^2/r^2).
// exp(-|x|^2/r^2) cancels in num/den ->
//   k' = exp2( fma(px,ax, fma(py,ay, fma(pz,az, aw))) )
//   a = (c2*yx, c2*yy, c2*yz, cy*|y|^2), c2=2*log2e/r^2, cy=-log2e/r^2.
//
// R7: DISCRIMINATOR. R5 instrumented this exact structure (scalar fma,
// PPT=8, CHUNK=32, SC=64, bounds 4, 1024 blocks) at 16.4us/rep steady-state,
// VALUBusy 88%. This round runs it clean (REPS=1). pk_fma (R6) was a
// non-lever: gfx950 fp32 peak is 157TF packed or scalar.
// Predict 21-25us (main 17 + combine 4 + overhead 2). If ~33us instead,
// a fixed per-replay overhead dominates -> fuse to one dispatch next.

constexpr int B_ = 4, N_ = 8192, S_ = 2048;
constexpr int BLOCK = 256, PPT = 8;
constexpr int PTS_PER_BLOCK = BLOCK * PPT;      // 2048
constexpr int NBPB = N_ / PTS_PER_BLOCK;        // 4
constexpr int NB = B_ * NBPB;                   // 16
constexpr int BN = B_ * N_;                     // 32768
constexpr float LOG2E = 1.4426950408889634f;

template <int CHUNK>
__global__ __launch_bounds__(BLOCK, 4) void uf2_main(
    const float* __restrict__ xyz,
    const float* __restrict__ sxyz,
    const float* __restrict__ sflow,
    const int* __restrict__ resol,
    float4* __restrict__ part)
{
    __shared__ float4 As[CHUNK];   // (c2*yx, c2*yy, c2*yz, cy*|y|^2)
    __shared__ float4 Fs[CHUNK];   // (fx, fy, fz, unused)

    const int nb = blockIdx.x % NB;
    const int sc = blockIdx.x / NB;
    const int b  = nb / NBPB;
    const int n0 = (nb % NBPB) * PTS_PER_BLOCK;
    const int s0 = sc * CHUNK;

    const float r = (float)resol[0];            // INITIAL_RADIUS(=1)*resol
    const float inv_r2 = 1.0f / (r * r);
    const float c2 = 2.0f * inv_r2 * LOG2E;
    const float cy = -inv_r2 * LOG2E;

    // ---- stage + pack sparse chunk into LDS ----
    const float* yb = sxyz  + b * 3 * S_;
    const float* fb = sflow + b * 3 * S_;
    for (int t = threadIdx.x; t < CHUNK; t += BLOCK) {
        const int s = s0 + t;
        const float yx = yb[s], yy = yb[S_ + s], yz = yb[2 * S_ + s];
        const float fx = fb[s], fy = fb[S_ + s], fz = fb[2 * S_ + s];
        As[t] = make_float4(c2 * yx, c2 * yy, c2 * yz,
                            cy * (yx * yx + yy * yy + yz * yz));
        Fs[t] = make_float4(fx, fy, fz, 0.0f);
    }
    __syncthreads();

    // ---- per-thread query points ----
    const float* xb = xyz + b * 3 * N_;
    float px[PPT], py[PPT], pz[PPT];
    float ax[PPT], ay[PPT], az[PPT], aw[PPT];
#pragma unroll
    for (int p = 0; p < PPT; ++p) {
        const int n = n0 + threadIdx.x + p * BLOCK;
        px[p] = xb[n]; py[p] = xb[N_ + n]; pz[p] = xb[2 * N_ + n];
        ax[p] = 0.f; ay[p] = 0.f; az[p] = 0.f; aw[p] = 0.f;
    }

    // ---- main loop (identical codegen to R5's measured inner loop) ----
#pragma unroll 2
    for (int t = 0; t < CHUNK; ++t) {
        const float4 a = As[t];   // broadcast ds_read_b128
        const float4 f = Fs[t];
#pragma unroll
        for (int p = 0; p < PPT; ++p) {
            float e = fmaf(pz[p], a.z, a.w);
            e = fmaf(py[p], a.y, e);
            e = fmaf(px[p], a.x, e);
            const float k = __builtin_amdgcn_exp2f(e);
            ax[p] = fmaf(k, f.x, ax[p]);
            ay[p] = fmaf(k, f.y, ay[p]);
            az[p] = fmaf(k, f.z, az[p]);
            aw[p] += k;
        }
    }

    // ---- write partials (coalesced float4) ----
#pragma unroll
    for (int p = 0; p < PPT; ++p) {
        const int g = b * N_ + n0 + threadIdx.x + p * BLOCK;
        part[(size_t)sc * BN + g] = make_float4(ax[p], ay[p], az[p], aw[p]);
    }
}

__global__ __launch_bounds__(BLOCK) void uf2_combine(
    const float4* __restrict__ part, float* __restrict__ out, int SC)
{
    const int g = blockIdx.x * BLOCK + threadIdx.x;   // 0..BN-1
    // 4 independent partial sums -> memory-level parallelism
    float4 s0 = make_float4(0.f, 0.f, 0.f, 0.f);
    float4 s1 = s0, s2 = s0, s3 = s0;
    int c = 0;
    for (; c + 4 <= SC; c += 4) {
        const float4 p0 = part[(size_t)(c + 0) * BN + g];
        const float4 p1 = part[(size_t)(c + 1) * BN + g];
        const float4 p2 = part[(size_t)(c + 2) * BN + g];
        const float4 p3 = part[(size_t)(c + 3) * BN + g];
        s0.x += p0.x; s0.y += p0.y; s0.z += p0.z; s0.w += p0.w;
        s1.x += p1.x; s1.y += p1.y; s1.z += p1.z; s1.w += p1.w;
        s2.x += p2.x; s2.y += p2.y; s2.z += p2.z; s2.w += p2.w;
        s3.x += p3.x; s3.y += p3.y; s3.z += p3.z; s3.w += p3.w;
    }
    for (; c < SC; ++c) {
        const float4 p = part[(size_t)c * BN + g];
        s0.x += p.x; s0.y += p.y; s0.z += p.z; s0.w += p.w;
    }
    const float sx = (s0.x + s1.x) + (s2.x + s3.x);
    const float sy = (s0.y + s1.y) + (s2.y + s3.y);
    const float sz = (s0.z + s1.z) + (s2.z + s3.z);
    const float sw = (s0.w + s1.w) + (s2.w + s3.w);
    const float inv = 1.0f / sw;
    const int b = g >> 13;            // /8192
    const int n = g & (N_ - 1);
    float* ob = out + b * 3 * N_;
    ob[n]          = sx * inv;
    ob[N_ + n]     = sy * inv;
    ob[2 * N_ + n] = sz * inv;
}

// Fallback (ws too small): single kernel, full S staged in LDS, direct out.
__global__ __launch_bounds__(BLOCK, 1) void uf2_fused(
    const float* __restrict__ xyz,
    const float* __restrict__ sxyz,
    const float* __restrict__ sflow,
    const int* __restrict__ resol,
    float* __restrict__ out)
{
    constexpr int FPPT = 4;
    constexpr int PTS = BLOCK * FPPT;
    __shared__ float4 As[S_];
    __shared__ float4 Fs[S_];

    const int nb = blockIdx.x;
    const int b  = nb / (N_ / PTS);
    const int n0 = (nb % (N_ / PTS)) * PTS;

    const float r = (float)resol[0];
    const float inv_r2 = 1.0f / (r * r);
    const float c2 = 2.0f * inv_r2 * LOG2E;
    const float cy = -inv_r2 * LOG2E;

    const float* yb = sxyz  + b * 3 * S_;
    const float* fb = sflow + b * 3 * S_;
    for (int t = threadIdx.x; t < S_; t += BLOCK) {
        const float yx = yb[t], yy = yb[S_ + t], yz = yb[2 * S_ + t];
        const float fx = fb[t], fy = fb[S_ + t], fz = fb[2 * S_ + t];
        As[t] = make_float4(c2 * yx, c2 * yy, c2 * yz,
                            cy * (yx * yx + yy * yy + yz * yz));
        Fs[t] = make_float4(fx, fy, fz, 0.0f);
    }
    __syncthreads();

    const float* xb = xyz + b * 3 * N_;
    float px[FPPT], py[FPPT], pz[FPPT];
    float4 acc[FPPT];
#pragma unroll
    for (int p = 0; p < FPPT; ++p) {
        const int n = n0 + threadIdx.x + p * BLOCK;
        px[p] = xb[n]; py[p] = xb[N_ + n]; pz[p] = xb[2 * N_ + n];
        acc[p] = make_float4(0.f, 0.f, 0.f, 0.f);
    }
#pragma unroll 4
    for (int t = 0; t < S_; ++t) {
        const float4 a = As[t];
        const float4 f = Fs[t];
#pragma unroll
        for (int p = 0; p < FPPT; ++p) {
            float e = fmaf(pz[p], a.z, a.w);
            e = fmaf(py[p], a.y, e);
            e = fmaf(px[p], a.x, e);
            const float k = __builtin_amdgcn_exp2f(e);
            acc[p].x = fmaf(k, f.x, acc[p].x);
            acc[p].y = fmaf(k, f.y, acc[p].y);
            acc[p].z = fmaf(k, f.z, acc[p].z);
            acc[p].w += k;
        }
    }
#pragma unroll
    for (int p = 0; p < FPPT; ++p) {
        const int n = n0 + threadIdx.x + p * BLOCK;
        const float inv = 1.0f / acc[p].w;
        float* ob = out + b * 3 * N_;
        ob[n]          = acc[p].x * inv;
        ob[N_ + n]     = acc[p].y * inv;
        ob[2 * N_ + n] = acc[p].z * inv;
    }
}

extern "C" void kernel_launch(void* const* d_in, const int* in_sizes, int n_in,
                              void* d_out, int out_size, void* d_ws, size_t ws_size,
                              hipStream_t stream)
{
    const float* xyz   = (const float*)d_in[0];
    const float* sxyz  = (const float*)d_in[1];
    const float* sflow = (const float*)d_in[2];
    const int*   resol = (const int*)d_in[3];
    float* out = (float*)d_out;
    float4* part = (float4*)d_ws;

    const size_t per_chunk = (size_t)BN * sizeof(float4);   // 512 KB
    int SC = 64;
    while (SC > 1 && (size_t)SC * per_chunk > ws_size) SC >>= 1;

    if ((size_t)SC * per_chunk > ws_size) {
        uf2_fused<<<dim3(BN / 1024), dim3(BLOCK), 0, stream>>>(
            xyz, sxyz, sflow, resol, out);
        return;
    }

    dim3 grid(NB * SC), blk(BLOCK);
    switch (SC) {
        case 64: uf2_main<S_ / 64><<<grid, blk, 0, stream>>>(xyz, sxyz, sflow, resol, part); break;
        case 32: uf2_main<S_ / 32><<<grid, blk, 0, stream>>>(xyz, sxyz, sflow, resol, part); break;
        case 16: uf2_main<S_ / 16><<<grid, blk, 0, stream>>>(xyz, sxyz, sflow, resol, part); break;
        case 8:  uf2_main<S_ / 8 ><<<grid, blk, 0, stream>>>(xyz, sxyz, sflow, resol, part); break;
        case 4:  uf2_main<S_ / 4 ><<<grid, blk, 0, stream>>>(xyz, sxyz, sflow, resol, part); break;
        case 2:  uf2_main<S_ / 2 ><<<grid, blk, 0, stream>>>(xyz, sxyz, sflow, resol, part); break;
        default: uf2_main<S_     ><<<grid, blk, 0, stream>>>(xyz, sxyz, sflow, resol, part); break;
    }
    uf2_combine<<<dim3(BN / BLOCK), dim3(BLOCK), 0, stream>>>(part, out, SC);
}

// Round 8
// 31.252 us; speedup vs baseline: 1.2385x; 1.2385x over previous
//
#include <hip/hip_runtime.h>

// UpsampleFlow2: Gaussian Nadaraya-Watson upsampling.
// out [B,3,N] = (sum_s k*f)/(sum_s k), k = exp(-|x-y|^2/r^2).
// exp(-|x|^2/r^2) cancels in num/den ->
//   k' = exp2( fma(px,ax, fma(py,ay, fma(pz,az, aw))) )
//   a = (c2*yx, c2*yy, c2*yz, cy*|y|^2), c2=2*log2e/r^2, cy=-log2e/r^2.
//
// R8: cost model fitted from R1/R2/R5/R6/R7:
//   total ~= inner(PPT) + 0.27us/MB * 2*SC*0.5MB + ~9us base
// Inner is minimized at PPT=8 (13.9us marginal, measured R5-R7).
// Partial traffic minimized at SC=16 while keeping 256 blocks = 1/CU,
// 16 waves/CU = 4 waves/SIMD (same occupancy R5 measured 13.9us at).
// Predict 26-28us.

constexpr int B_ = 4, N_ = 8192, S_ = 2048;
constexpr int BLOCK = 256, PPT = 8;
constexpr int PTS_PER_BLOCK = BLOCK * PPT;      // 2048
constexpr int NBPB = N_ / PTS_PER_BLOCK;        // 4
constexpr int NB = B_ * NBPB;                   // 16
constexpr int BN = B_ * N_;                     // 32768
constexpr float LOG2E = 1.4426950408889634f;

template <int CHUNK>
__global__ __launch_bounds__(BLOCK, 4) void uf2_main(
    const float* __restrict__ xyz,
    const float* __restrict__ sxyz,
    const float* __restrict__ sflow,
    const int* __restrict__ resol,
    float4* __restrict__ part)
{
    __shared__ float4 As[CHUNK];   // (c2*yx, c2*yy, c2*yz, cy*|y|^2)
    __shared__ float4 Fs[CHUNK];   // (fx, fy, fz, unused)

    const int nb = blockIdx.x % NB;
    const int sc = blockIdx.x / NB;
    const int b  = nb / NBPB;
    const int n0 = (nb % NBPB) * PTS_PER_BLOCK;
    const int s0 = sc * CHUNK;

    const float r = (float)resol[0];            // INITIAL_RADIUS(=1)*resol
    const float inv_r2 = 1.0f / (r * r);
    const float c2 = 2.0f * inv_r2 * LOG2E;
    const float cy = -inv_r2 * LOG2E;

    // ---- stage + pack sparse chunk into LDS ----
    const float* yb = sxyz  + b * 3 * S_;
    const float* fb = sflow + b * 3 * S_;
    for (int t = threadIdx.x; t < CHUNK; t += BLOCK) {
        const int s = s0 + t;
        const float yx = yb[s], yy = yb[S_ + s], yz = yb[2 * S_ + s];
        const float fx = fb[s], fy = fb[S_ + s], fz = fb[2 * S_ + s];
        As[t] = make_float4(c2 * yx, c2 * yy, c2 * yz,
                            cy * (yx * yx + yy * yy + yz * yz));
        Fs[t] = make_float4(fx, fy, fz, 0.0f);
    }
    __syncthreads();

    // ---- per-thread query points ----
    const float* xb = xyz + b * 3 * N_;
    float px[PPT], py[PPT], pz[PPT];
    float ax[PPT], ay[PPT], az[PPT], aw[PPT];
#pragma unroll
    for (int p = 0; p < PPT; ++p) {
        const int n = n0 + threadIdx.x + p * BLOCK;
        px[p] = xb[n]; py[p] = xb[N_ + n]; pz[p] = xb[2 * N_ + n];
        ax[p] = 0.f; ay[p] = 0.f; az[p] = 0.f; aw[p] = 0.f;
    }

    // ---- main loop (R5-measured codegen: 13.9us marginal at 4 w/SIMD) ----
#pragma unroll 2
    for (int t = 0; t < CHUNK; ++t) {
        const float4 a = As[t];   // broadcast ds_read_b128
        const float4 f = Fs[t];
#pragma unroll
        for (int p = 0; p < PPT; ++p) {
            float e = fmaf(pz[p], a.z, a.w);
            e = fmaf(py[p], a.y, e);
            e = fmaf(px[p], a.x, e);
            const float k = __builtin_amdgcn_exp2f(e);
            ax[p] = fmaf(k, f.x, ax[p]);
            ay[p] = fmaf(k, f.y, ay[p]);
            az[p] = fmaf(k, f.z, az[p]);
            aw[p] += k;
        }
    }

    // ---- write partials (coalesced float4) ----
#pragma unroll
    for (int p = 0; p < PPT; ++p) {
        const int g = b * N_ + n0 + threadIdx.x + p * BLOCK;
        part[(size_t)sc * BN + g] = make_float4(ax[p], ay[p], az[p], aw[p]);
    }
}

__global__ __launch_bounds__(BLOCK) void uf2_combine(
    const float4* __restrict__ part, float* __restrict__ out, int SC)
{
    const int g = blockIdx.x * BLOCK + threadIdx.x;   // 0..BN-1
    // 4 independent partial sums -> memory-level parallelism
    float4 s0 = make_float4(0.f, 0.f, 0.f, 0.f);
    float4 s1 = s0, s2 = s0, s3 = s0;
    int c = 0;
    for (; c + 4 <= SC; c += 4) {
        const float4 p0 = part[(size_t)(c + 0) * BN + g];
        const float4 p1 = part[(size_t)(c + 1) * BN + g];
        const float4 p2 = part[(size_t)(c + 2) * BN + g];
        const float4 p3 = part[(size_t)(c + 3) * BN + g];
        s0.x += p0.x; s0.y += p0.y; s0.z += p0.z; s0.w += p0.w;
        s1.x += p1.x; s1.y += p1.y; s1.z += p1.z; s1.w += p1.w;
        s2.x += p2.x; s2.y += p2.y; s2.z += p2.z; s2.w += p2.w;
        s3.x += p3.x; s3.y += p3.y; s3.z += p3.z; s3.w += p3.w;
    }
    for (; c < SC; ++c) {
        const float4 p = part[(size_t)c * BN + g];
        s0.x += p.x; s0.y += p.y; s0.z += p.z; s0.w += p.w;
    }
    const float sx = (s0.x + s1.x) + (s2.x + s3.x);
    const float sy = (s0.y + s1.y) + (s2.y + s3.y);
    const float sz = (s0.z + s1.z) + (s2.z + s3.z);
    const float sw = (s0.w + s1.w) + (s2.w + s3.w);
    const float inv = 1.0f / sw;
    const int b = g >> 13;            // /8192
    const int n = g & (N_ - 1);
    float* ob = out + b * 3 * N_;
    ob[n]          = sx * inv;
    ob[N_ + n]     = sy * inv;
    ob[2 * N_ + n] = sz * inv;
}

// Fallback (ws too small): single kernel, full S staged in LDS, direct out.
__global__ __launch_bounds__(BLOCK, 1) void uf2_fused(
    const float* __restrict__ xyz,
    const float* __restrict__ sxyz,
    const float* __restrict__ sflow,
    const int* __restrict__ resol,
    float* __restrict__ out)
{
    constexpr int FPPT = 4;
    constexpr int PTS = BLOCK * FPPT;
    __shared__ float4 As[S_];
    __shared__ float4 Fs[S_];

    const int nb = blockIdx.x;
    const int b  = nb / (N_ / PTS);
    const int n0 = (nb % (N_ / PTS)) * PTS;

    const float r = (float)resol[0];
    const float inv_r2 = 1.0f / (r * r);
    const float c2 = 2.0f * inv_r2 * LOG2E;
    const float cy = -inv_r2 * LOG2E;

    const float* yb = sxyz  + b * 3 * S_;
    const float* fb = sflow + b * 3 * S_;
    for (int t = threadIdx.x; t < S_; t += BLOCK) {
        const float yx = yb[t], yy = yb[S_ + t], yz = yb[2 * S_ + t];
        const float fx = fb[t], fy = fb[S_ + t], fz = fb[2 * S_ + t];
        As[t] = make_float4(c2 * yx, c2 * yy, c2 * yz,
                            cy * (yx * yx + yy * yy + yz * yz));
        Fs[t] = make_float4(fx, fy, fz, 0.0f);
    }
    __syncthreads();

    const float* xb = xyz + b * 3 * N_;
    float px[FPPT], py[FPPT], pz[FPPT];
    float4 acc[FPPT];
#pragma unroll
    for (int p = 0; p < FPPT; ++p) {
        const int n = n0 + threadIdx.x + p * BLOCK;
        px[p] = xb[n]; py[p] = xb[N_ + n]; pz[p] = xb[2 * N_ + n];
        acc[p] = make_float4(0.f, 0.f, 0.f, 0.f);
    }
#pragma unroll 4
    for (int t = 0; t < S_; ++t) {
        const float4 a = As[t];
        const float4 f = Fs[t];
#pragma unroll
        for (int p = 0; p < FPPT; ++p) {
            float e = fmaf(pz[p], a.z, a.w);
            e = fmaf(py[p], a.y, e);
            e = fmaf(px[p], a.x, e);
            const float k = __builtin_amdgcn_exp2f(e);
            acc[p].x = fmaf(k, f.x, acc[p].x);
            acc[p].y = fmaf(k, f.y, acc[p].y);
            acc[p].z = fmaf(k, f.z, acc[p].z);
            acc[p].w += k;
        }
    }
#pragma unroll
    for (int p = 0; p < FPPT; ++p) {
        const int n = n0 + threadIdx.x + p * BLOCK;
        const float inv = 1.0f / acc[p].w;
        float* ob = out + b * 3 * N_;
        ob[n]          = acc[p].x * inv;
        ob[N_ + n]     = acc[p].y * inv;
        ob[2 * N_ + n] = acc[p].z * inv;
    }
}

extern "C" void kernel_launch(void* const* d_in, const int* in_sizes, int n_in,
                              void* d_out, int out_size, void* d_ws, size_t ws_size,
                              hipStream_t stream)
{
    const float* xyz   = (const float*)d_in[0];
    const float* sxyz  = (const float*)d_in[1];
    const float* sflow = (const float*)d_in[2];
    const int*   resol = (const int*)d_in[3];
    float* out = (float*)d_out;
    float4* part = (float4*)d_ws;

    const size_t per_chunk = (size_t)BN * sizeof(float4);   // 512 KB
    int SC = 16;
    while (SC > 1 && (size_t)SC * per_chunk > ws_size) SC >>= 1;

    if ((size_t)SC * per_chunk > ws_size) {
        uf2_fused<<<dim3(BN / 1024), dim3(BLOCK), 0, stream>>>(
            xyz, sxyz, sflow, resol, out);
        return;
    }

    dim3 grid(NB * SC), blk(BLOCK);
    switch (SC) {
        case 16: uf2_main<S_ / 16><<<grid, blk, 0, stream>>>(xyz, sxyz, sflow, resol, part); break;
        case 8:  uf2_main<S_ / 8 ><<<grid, blk, 0, stream>>>(xyz, sxyz, sflow, resol, part); break;
        case 4:  uf2_main<S_ / 4 ><<<grid, blk, 0, stream>>>(xyz, sxyz, sflow, resol, part); break;
        case 2:  uf2_main<S_ / 2 ><<<grid, blk, 0, stream>>>(xyz, sxyz, sflow, resol, part); break;
        default: uf2_main<S_     ><<<grid, blk, 0, stream>>>(xyz, sxyz, sflow, resol, part); break;
    }
    uf2_combine<<<dim3(BN / BLOCK), dim3(BLOCK), 0, stream>>>(part, out, SC);
}